// Round 1
// baseline (1241.729 us; speedup 1.0000x reference)
//
#include <hip/hip_runtime.h>
#include <hip/hip_bf16.h>
#include <math.h>

#define D 128
constexpr int NT = 64;  // nodes per block in node_transform

// ---------------------------------------------------------------------------
// K0: zero agg[N*D] + denom[N] (contiguous in ws)
// ---------------------------------------------------------------------------
__global__ __launch_bounds__(256) void zero_ws_kernel(float4* __restrict__ p, int n4) {
    int i = blockIdx.x * blockDim.x + threadIdx.x;
    if (i < n4) p[i] = make_float4(0.f, 0.f, 0.f, 0.f);
}

// ---------------------------------------------------------------------------
// K1: z = h @ W_func^T  (blockIdx.y==0)   h_s = h @ W_self^T (blockIdx.y==1)
// 64-node tile in LDS; thread t: oi = t&63 -> outputs {oi, oi+64},
// q = t>>6 -> nodes [q*16, q*16+16). 8 FMA per ds_read_b128.
// ---------------------------------------------------------------------------
__global__ __launch_bounds__(256) void node_transform(
    const float* __restrict__ h, const float* __restrict__ Wf,
    const float* __restrict__ Ws, float* __restrict__ z,
    float* __restrict__ hs_out, int N)
{
    __shared__ float tile[NT * D];  // 32 KB
    const int t = threadIdx.x;
    const int n0 = blockIdx.x * NT;
    const float* __restrict__ W = (blockIdx.y == 0) ? Wf : Ws;
    float* __restrict__ out = (blockIdx.y == 0) ? z : hs_out;
    const int nvalid = min(NT, N - n0);

    // stage h tile: NT*D floats = 2048 float4; 8 float4 per thread, coalesced
    {
        const float4* __restrict__ src4 = (const float4*)(h + (size_t)n0 * D);
        float4* dst4 = (float4*)tile;
        #pragma unroll
        for (int i = 0; i < 8; ++i) {
            int idx = t + i * 256;               // float4 index; node = idx>>5
            float4 v = make_float4(0.f, 0.f, 0.f, 0.f);
            if ((idx >> 5) < nvalid) v = src4[idx];
            dst4[idx] = v;
        }
    }
    __syncthreads();

    const int oi = t & 63;
    const int q  = t >> 6;
    float acc0[16], acc1[16];
    #pragma unroll
    for (int n = 0; n < 16; ++n) { acc0[n] = 0.f; acc1[n] = 0.f; }

    const float* __restrict__ w0p = W + (size_t)oi * D;
    const float* __restrict__ w1p = W + (size_t)(oi + 64) * D;

    for (int kk = 0; kk < D; kk += 8) {
        float4 w00 = *(const float4*)(w0p + kk);
        float4 w01 = *(const float4*)(w0p + kk + 4);
        float4 w10 = *(const float4*)(w1p + kk);
        float4 w11 = *(const float4*)(w1p + kk + 4);
        #pragma unroll
        for (int n = 0; n < 16; ++n) {
            const float* hp = &tile[(q * 16 + n) * D + kk];
            float4 a = *(const float4*)hp;
            float4 b = *(const float4*)(hp + 4);
            acc0[n] += a.x * w00.x + a.y * w00.y + a.z * w00.z + a.w * w00.w
                     + b.x * w01.x + b.y * w01.y + b.z * w01.z + b.w * w01.w;
            acc1[n] += a.x * w10.x + a.y * w10.y + a.z * w10.z + a.w * w10.w
                     + b.x * w11.x + b.y * w11.y + b.z * w11.z + b.w * w11.w;
        }
    }

    #pragma unroll
    for (int n = 0; n < 16; ++n) {
        int node = q * 16 + n;
        if (node < nvalid) {
            size_t base = (size_t)(n0 + node) * D;
            out[base + oi]      = acc0[n];
            out[base + oi + 64] = acc1[n];
        }
    }
}

// ---------------------------------------------------------------------------
// K2: per-node attention scores s_src = z . wa[:D], s_dst = z . wa[D:2D]
// One wave per node; butterfly reduce.
// ---------------------------------------------------------------------------
__global__ __launch_bounds__(256) void node_scores(
    const float* __restrict__ z, const float* __restrict__ wa,
    float* __restrict__ s_src, float* __restrict__ s_dst, int N)
{
    const int lane = threadIdx.x & 63;
    const int n = blockIdx.x * 4 + (threadIdx.x >> 6);
    if (n >= N) return;
    float2 zv = *(const float2*)(z + (size_t)n * D + 2 * lane);
    float a = zv.x * wa[2 * lane]     + zv.y * wa[2 * lane + 1];
    float b = zv.x * wa[D + 2 * lane] + zv.y * wa[D + 2 * lane + 1];
    #pragma unroll
    for (int off = 32; off > 0; off >>= 1) {
        a += __shfl_xor(a, off, 64);
        b += __shfl_xor(b, off, 64);
    }
    if (lane == 0) { s_src[n] = a; s_dst[n] = b; }
}

// ---------------------------------------------------------------------------
// K3: edge pass. One wave per edge (grid-stride).
//  ex = exp(leaky_relu(s_src[s] + s_dst[d] + edge_w[e].wa_e))    (no max-sub:
//  logits are O(15), exp is fp32-safe; softmax is shift-invariant)
//  denom[d] += ex;  agg[d][:] += ex * z[s][:]   (normalization deferred)
// ---------------------------------------------------------------------------
__global__ __launch_bounds__(256) void edge_kernel(
    const float* __restrict__ edge_w, const float* __restrict__ wa,
    const int* __restrict__ src, const int* __restrict__ dst,
    const float* __restrict__ s_src, const float* __restrict__ s_dst,
    const float* __restrict__ z, float* __restrict__ denom,
    float* __restrict__ agg, int E)
{
    const int lane = threadIdx.x & 63;
    const int wid = blockIdx.x * (blockDim.x >> 6) + (threadIdx.x >> 6);
    const int nw  = gridDim.x * (blockDim.x >> 6);
    const float we0 = wa[2 * D + 2 * lane];
    const float we1 = wa[2 * D + 2 * lane + 1];
    for (int e = wid; e < E; e += nw) {
        const int s = src[e];
        const int d = dst[e];
        float2 ew = *(const float2*)(edge_w + (size_t)e * D + 2 * lane);
        float part = ew.x * we0 + ew.y * we1;
        #pragma unroll
        for (int off = 32; off > 0; off >>= 1) part += __shfl_xor(part, off, 64);
        float logit = s_src[s] + s_dst[d] + part;
        logit = (logit > 0.f) ? logit : 0.01f * logit;
        float ex = __expf(logit);
        if (lane == 0) atomicAdd(denom + d, ex);
        float2 zv = *(const float2*)(z + (size_t)s * D + 2 * lane);
        float* ap = agg + (size_t)d * D + 2 * lane;
        atomicAdd(ap,     ex * zv.x);
        atomicAdd(ap + 1, ex * zv.y);
    }
}

// ---------------------------------------------------------------------------
// K4: epilogue. out = h + relu(denom>0 ? h_s + agg/denom : h)
// h_s lives in d_out; same-index read->write is safe.
// ---------------------------------------------------------------------------
__global__ __launch_bounds__(256) void finalize(
    const float* __restrict__ h, const float* __restrict__ h_s,
    const float* __restrict__ agg, const float* __restrict__ denom,
    float* __restrict__ out, int N)
{
    int idx = blockIdx.x * blockDim.x + threadIdx.x;  // float4 index
    int total = N * (D / 4);
    if (idx >= total) return;
    int node = idx >> 5;  // D/4 = 32 float4 per node
    float dn = denom[node];
    float4 hv = ((const float4*)h)[idx];
    float4 r;
    if (dn > 0.f) {
        float inv = 1.f / fmaxf(dn, 1e-9f);
        float4 hs = ((const float4*)h_s)[idx];
        float4 ag = ((const float4*)agg)[idx];
        r.x = hs.x + ag.x * inv;
        r.y = hs.y + ag.y * inv;
        r.z = hs.z + ag.z * inv;
        r.w = hs.w + ag.w * inv;
    } else {
        r = hv;
    }
    r.x = fmaxf(r.x, 0.f); r.y = fmaxf(r.y, 0.f);
    r.z = fmaxf(r.z, 0.f); r.w = fmaxf(r.w, 0.f);
    float4 o;
    o.x = hv.x + r.x; o.y = hv.y + r.y; o.z = hv.z + r.z; o.w = hv.w + r.w;
    ((float4*)out)[idx] = o;
}

// ---------------------------------------------------------------------------
extern "C" void kernel_launch(void* const* d_in, const int* in_sizes, int n_in,
                              void* d_out, int out_size, void* d_ws, size_t ws_size,
                              hipStream_t stream)
{
    const float* h      = (const float*)d_in[0];
    const float* edge_w = (const float*)d_in[1];
    const float* W_self = (const float*)d_in[2];
    const float* W_func = (const float*)d_in[3];
    const float* W_att  = (const float*)d_in[4];
    const int*   src    = (const int*)d_in[5];
    const int*   dst    = (const int*)d_in[6];
    float* out = (float*)d_out;

    const int N = in_sizes[0] / D;   // 50000
    const int E = in_sizes[1] / D;   // 800000

    // workspace layout (floats): [agg N*D][denom N][z N*D][s_src N][s_dst N]
    float* ws_f  = (float*)d_ws;
    float* agg   = ws_f;
    float* denom = ws_f + (size_t)N * D;
    float* z     = ws_f + (size_t)N * D + N;
    float* s_src = ws_f + 2 * (size_t)N * D + N;
    float* s_dst = ws_f + 2 * (size_t)N * D + 2 * N;
    // h_s goes into d_out (finalize reads/writes same index — safe)

    // K0: zero agg + denom (contiguous, (N*D+N) divisible by 4)
    {
        int n4 = (N * D + N) / 4;
        int blocks = (n4 + 255) / 256;
        zero_ws_kernel<<<blocks, 256, 0, stream>>>((float4*)agg, n4);
    }
    // K1: node transforms (y=0 -> z, y=1 -> h_s in d_out)
    {
        dim3 grid((N + NT - 1) / NT, 2);
        node_transform<<<grid, 256, 0, stream>>>(h, W_func, W_self, z, out, N);
    }
    // K2: per-node attention scores
    {
        int blocks = (N + 3) / 4;
        node_scores<<<blocks, 256, 0, stream>>>(z, W_att, s_src, s_dst, N);
    }
    // K3: edge pass (wave per edge, grid-stride)
    {
        edge_kernel<<<2048, 256, 0, stream>>>(edge_w, W_att, src, dst,
                                              s_src, s_dst, z, denom, agg, E);
    }
    // K4: epilogue
    {
        int total4 = N * (D / 4);
        int blocks = (total4 + 255) / 256;
        finalize<<<blocks, 256, 0, stream>>>(h, out, agg, denom, out, N);
    }
}

// Round 2
// 934.240 us; speedup vs baseline: 1.3291x; 1.3291x over previous
//
#include <hip/hip_runtime.h>
#include <hip/hip_bf16.h>
#include <math.h>

#define D 128
constexpr int NT = 64;  // nodes per block in node_transform

// ---------------------------------------------------------------------------
// K0: zero deg[N]
// ---------------------------------------------------------------------------
__global__ __launch_bounds__(256) void zero_int(int* __restrict__ p, int n) {
    int i = blockIdx.x * blockDim.x + threadIdx.x;
    if (i < n) p[i] = 0;
}

// ---------------------------------------------------------------------------
// K1: z = h @ W_func^T (blockIdx.y==0)   h_s = h @ W_self^T (blockIdx.y==1)
// 64-node tile in LDS; thread t: oi = t&63 -> outputs {oi, oi+64},
// q = t>>6 -> nodes [q*16, q*16+16). 8 FMA per ds_read_b128.
// ---------------------------------------------------------------------------
__global__ __launch_bounds__(256) void node_transform(
    const float* __restrict__ h, const float* __restrict__ Wf,
    const float* __restrict__ Ws, float* __restrict__ z,
    float* __restrict__ hs_out, int N)
{
    __shared__ float tile[NT * D];  // 32 KB
    const int t = threadIdx.x;
    const int n0 = blockIdx.x * NT;
    const float* __restrict__ W = (blockIdx.y == 0) ? Wf : Ws;
    float* __restrict__ out = (blockIdx.y == 0) ? z : hs_out;
    const int nvalid = min(NT, N - n0);

    {
        const float4* __restrict__ src4 = (const float4*)(h + (size_t)n0 * D);
        float4* dst4 = (float4*)tile;
        #pragma unroll
        for (int i = 0; i < 8; ++i) {
            int idx = t + i * 256;               // float4 index; node = idx>>5
            float4 v = make_float4(0.f, 0.f, 0.f, 0.f);
            if ((idx >> 5) < nvalid) v = src4[idx];
            dst4[idx] = v;
        }
    }
    __syncthreads();

    const int oi = t & 63;
    const int q  = t >> 6;
    float acc0[16], acc1[16];
    #pragma unroll
    for (int n = 0; n < 16; ++n) { acc0[n] = 0.f; acc1[n] = 0.f; }

    const float* __restrict__ w0p = W + (size_t)oi * D;
    const float* __restrict__ w1p = W + (size_t)(oi + 64) * D;

    for (int kk = 0; kk < D; kk += 8) {
        float4 w00 = *(const float4*)(w0p + kk);
        float4 w01 = *(const float4*)(w0p + kk + 4);
        float4 w10 = *(const float4*)(w1p + kk);
        float4 w11 = *(const float4*)(w1p + kk + 4);
        #pragma unroll
        for (int n = 0; n < 16; ++n) {
            const float* hp = &tile[(q * 16 + n) * D + kk];
            float4 a = *(const float4*)hp;
            float4 b = *(const float4*)(hp + 4);
            acc0[n] += a.x * w00.x + a.y * w00.y + a.z * w00.z + a.w * w00.w
                     + b.x * w01.x + b.y * w01.y + b.z * w01.z + b.w * w01.w;
            acc1[n] += a.x * w10.x + a.y * w10.y + a.z * w10.z + a.w * w10.w
                     + b.x * w11.x + b.y * w11.y + b.z * w11.z + b.w * w11.w;
        }
    }

    #pragma unroll
    for (int n = 0; n < 16; ++n) {
        int node = q * 16 + n;
        if (node < nvalid) {
            size_t base = (size_t)(n0 + node) * D;
            out[base + oi]      = acc0[n];
            out[base + oi + 64] = acc1[n];
        }
    }
}

// ---------------------------------------------------------------------------
// K2: per-node attention scores s_src = z . wa[:D], s_dst = z . wa[D:2D]
// ---------------------------------------------------------------------------
__global__ __launch_bounds__(256) void node_scores(
    const float* __restrict__ z, const float* __restrict__ wa,
    float* __restrict__ s_src, float* __restrict__ s_dst, int N)
{
    const int lane = threadIdx.x & 63;
    const int n = blockIdx.x * 4 + (threadIdx.x >> 6);
    if (n >= N) return;
    float2 zv = *(const float2*)(z + (size_t)n * D + 2 * lane);
    float a = zv.x * wa[2 * lane]     + zv.y * wa[2 * lane + 1];
    float b = zv.x * wa[D + 2 * lane] + zv.y * wa[D + 2 * lane + 1];
    #pragma unroll
    for (int off = 32; off > 0; off >>= 1) {
        a += __shfl_xor(a, off, 64);
        b += __shfl_xor(b, off, 64);
    }
    if (lane == 0) { s_src[n] = a; s_dst[n] = b; }
}

// ---------------------------------------------------------------------------
// K3a: histogram of dst -> deg[N]
// ---------------------------------------------------------------------------
__global__ __launch_bounds__(256) void hist_kernel(
    const int* __restrict__ dst, int* __restrict__ deg, int E)
{
    int e = blockIdx.x * blockDim.x + threadIdx.x;
    if (e < E) atomicAdd(deg + dst[e], 1);
}

// ---------------------------------------------------------------------------
// K3b/c/d: 3-phase exclusive scan of deg -> off, cursor (NB <= 256 blocks)
// ---------------------------------------------------------------------------
__global__ __launch_bounds__(256) void scan_block_sums(
    const int* __restrict__ deg, int* __restrict__ bsum, int N)
{
    __shared__ int s[256];
    int i = blockIdx.x * 256 + threadIdx.x;
    s[threadIdx.x] = (i < N) ? deg[i] : 0;
    for (int o = 128; o > 0; o >>= 1) {
        __syncthreads();
        if (threadIdx.x < o) s[threadIdx.x] += s[threadIdx.x + o];
    }
    if (threadIdx.x == 0) bsum[blockIdx.x] = s[0];
}

__global__ __launch_bounds__(256) void scan_bsum(
    const int* __restrict__ bsum, int* __restrict__ boff, int NB)
{
    __shared__ int s[256];
    int t = threadIdx.x;
    int v = (t < NB) ? bsum[t] : 0;
    s[t] = v;
    for (int o = 1; o < 256; o <<= 1) {
        __syncthreads();
        int x = (t >= o) ? s[t - o] : 0;
        __syncthreads();
        s[t] += x;
    }
    __syncthreads();
    if (t < NB) boff[t] = s[t] - v;   // exclusive
}

__global__ __launch_bounds__(256) void scan_final(
    const int* __restrict__ deg, const int* __restrict__ boff,
    int* __restrict__ off, int* __restrict__ cursor, int N)
{
    __shared__ int s[256];
    int t = threadIdx.x;
    int i = blockIdx.x * 256 + t;
    int v = (i < N) ? deg[i] : 0;
    s[t] = v;
    for (int o = 1; o < 256; o <<= 1) {
        __syncthreads();
        int x = (t >= o) ? s[t - o] : 0;
        __syncthreads();
        s[t] += x;
    }
    __syncthreads();
    if (i < N) {
        int ex = boff[blockIdx.x] + s[t] - v;
        off[i] = ex;
        cursor[i] = ex;
    }
}

// ---------------------------------------------------------------------------
// K3e: edge pass. One wave per edge (grid-stride).
//  ex = exp(leaky_relu(s_src[s] + s_dst[d] + edge_w[e].wa_e))
//  scatter {src, ex} into the dst bucket (1 atomic per edge, lane 0)
// ---------------------------------------------------------------------------
__global__ __launch_bounds__(256) void edge_pass(
    const float* __restrict__ edge_w, const float* __restrict__ wa,
    const int* __restrict__ src, const int* __restrict__ dst,
    const float* __restrict__ s_src, const float* __restrict__ s_dst,
    int* __restrict__ cursor, int* __restrict__ src_s,
    float* __restrict__ ex_s, int E)
{
    const int lane = threadIdx.x & 63;
    const int wid = blockIdx.x * 4 + (threadIdx.x >> 6);
    const int nw  = gridDim.x * 4;
    const float we0 = wa[2 * D + 2 * lane];
    const float we1 = wa[2 * D + 2 * lane + 1];
    for (int e = wid; e < E; e += nw) {
        const int s = src[e];
        const int d = dst[e];
        float2 ew = *(const float2*)(edge_w + (size_t)e * D + 2 * lane);
        float part = ew.x * we0 + ew.y * we1;
        #pragma unroll
        for (int o = 32; o > 0; o >>= 1) part += __shfl_xor(part, o, 64);
        float logit = s_src[s] + s_dst[d] + part;
        logit = (logit > 0.f) ? logit : 0.01f * logit;
        float ex = __expf(logit);
        if (lane == 0) {
            int pos = atomicAdd(cursor + d, 1);
            src_s[pos] = s;
            ex_s[pos]  = ex;
        }
    }
}

// ---------------------------------------------------------------------------
// K4: aggregation + epilogue, no atomics. One wave per dst node.
//  agg = sum_e ex*z[src_e]; denom = sum_e ex (local);
//  out = h + relu(deg>0 ? h_s + agg/denom : h)
//  (h_s lives in d_out; same-index read->write is safe)
// ---------------------------------------------------------------------------
__global__ __launch_bounds__(256) void agg_finalize(
    const int* __restrict__ off, const int* __restrict__ deg,
    const int* __restrict__ src_s, const float* __restrict__ ex_s,
    const float* __restrict__ z, const float* __restrict__ h,
    const float* __restrict__ h_s, float* __restrict__ out, int N)
{
    const int lane = threadIdx.x & 63;
    const int n = blockIdx.x * 4 + (threadIdx.x >> 6);
    if (n >= N) return;
    const int b  = off[n];
    const int dg = deg[n];
    float ax = 0.f, ay = 0.f, dsum = 0.f;
    for (int e = b; e < b + dg; ++e) {
        int s    = src_s[e];          // wave-uniform -> scalar load
        float ex = ex_s[e];
        dsum += ex;
        float2 zv = *(const float2*)(z + (size_t)s * D + 2 * lane);
        ax += ex * zv.x;
        ay += ex * zv.y;
    }
    float2 hv = *(const float2*)(h + (size_t)n * D + 2 * lane);
    float rx, ry;
    if (dg > 0) {
        float inv = 1.f / fmaxf(dsum, 1e-9f);
        float2 hs = *(const float2*)(h_s + (size_t)n * D + 2 * lane);
        rx = hs.x + ax * inv;
        ry = hs.y + ay * inv;
    } else {
        rx = hv.x; ry = hv.y;
    }
    rx = fmaxf(rx, 0.f); ry = fmaxf(ry, 0.f);
    float2 o = make_float2(hv.x + rx, hv.y + ry);
    *(float2*)(out + (size_t)n * D + 2 * lane) = o;
}

// ---------------------------------------------------------------------------
extern "C" void kernel_launch(void* const* d_in, const int* in_sizes, int n_in,
                              void* d_out, int out_size, void* d_ws, size_t ws_size,
                              hipStream_t stream)
{
    const float* h      = (const float*)d_in[0];
    const float* edge_w = (const float*)d_in[1];
    const float* W_self = (const float*)d_in[2];
    const float* W_func = (const float*)d_in[3];
    const float* W_att  = (const float*)d_in[4];
    const int*   src    = (const int*)d_in[5];
    const int*   dst    = (const int*)d_in[6];
    float* out = (float*)d_out;

    const int N = in_sizes[0] / D;   // 50000
    const int E = in_sizes[1] / D;   // 800000
    const int NB = (N + 255) / 256;  // 196 scan blocks (<= 256 required)

    // workspace layout
    float* z     = (float*)d_ws;           // N*D
    float* ex_s  = z + (size_t)N * D;      // E
    float* s_src = ex_s + E;               // N
    float* s_dst = s_src + N;              // N
    int*   src_s = (int*)(s_dst + N);      // E
    int*   deg   = src_s + E;              // N
    int*   off   = deg + N;                // N
    int*   cursor= off + N;                // N
    int*   bsum  = cursor + N;             // 256
    int*   boff  = bsum + 256;             // 256

    // K0: zero deg
    zero_int<<<(N + 255) / 256, 256, 0, stream>>>(deg, N);

    // K1: node transforms (y=0 -> z, y=1 -> h_s staged in d_out)
    {
        dim3 grid((N + NT - 1) / NT, 2);
        node_transform<<<grid, 256, 0, stream>>>(h, W_func, W_self, z, out, N);
    }
    // K2: per-node attention scores
    node_scores<<<(N + 3) / 4, 256, 0, stream>>>(z, W_att, s_src, s_dst, N);

    // K3: CSR build + edge pass
    hist_kernel<<<(E + 255) / 256, 256, 0, stream>>>(dst, deg, E);
    scan_block_sums<<<NB, 256, 0, stream>>>(deg, bsum, N);
    scan_bsum<<<1, 256, 0, stream>>>(bsum, boff, NB);
    scan_final<<<NB, 256, 0, stream>>>(deg, boff, off, cursor, N);
    edge_pass<<<2048, 256, 0, stream>>>(edge_w, W_att, src, dst,
                                        s_src, s_dst, cursor, src_s, ex_s, E);

    // K4: bucketed aggregation + epilogue (no atomics)
    agg_finalize<<<(N + 3) / 4, 256, 0, stream>>>(off, deg, src_s, ex_s,
                                                  z, h, out, out, N);
}

// Round 3
// 813.847 us; speedup vs baseline: 1.5258x; 1.1479x over previous
//
#include <hip/hip_runtime.h>
#include <hip/hip_bf16.h>
#include <math.h>

#define D 128
constexpr int NT = 64;  // nodes per block in node_transform

// ---------------------------------------------------------------------------
// K1: z = h @ W_func^T (blockIdx.y==0)   h_s = h @ W_self^T (blockIdx.y==1)
// 64-node tile in LDS; thread t: oi = t&63 -> outputs {oi, oi+64},
// q = t>>6 -> nodes [q*16, q*16+16). 8 FMA per ds_read_b128.
// ---------------------------------------------------------------------------
__global__ __launch_bounds__(256) void node_transform(
    const float* __restrict__ h, const float* __restrict__ Wf,
    const float* __restrict__ Ws, float* __restrict__ z,
    float* __restrict__ hs_out, int N)
{
    __shared__ float tile[NT * D];  // 32 KB
    const int t = threadIdx.x;
    const int n0 = blockIdx.x * NT;
    const float* __restrict__ W = (blockIdx.y == 0) ? Wf : Ws;
    float* __restrict__ out = (blockIdx.y == 0) ? z : hs_out;
    const int nvalid = min(NT, N - n0);

    {
        const float4* __restrict__ src4 = (const float4*)(h + (size_t)n0 * D);
        float4* dst4 = (float4*)tile;
        #pragma unroll
        for (int i = 0; i < 8; ++i) {
            int idx = t + i * 256;               // float4 index; node = idx>>5
            float4 v = make_float4(0.f, 0.f, 0.f, 0.f);
            if ((idx >> 5) < nvalid) v = src4[idx];
            dst4[idx] = v;
        }
    }
    __syncthreads();

    const int oi = t & 63;
    const int q  = t >> 6;
    float acc0[16], acc1[16];
    #pragma unroll
    for (int n = 0; n < 16; ++n) { acc0[n] = 0.f; acc1[n] = 0.f; }

    const float* __restrict__ w0p = W + (size_t)oi * D;
    const float* __restrict__ w1p = W + (size_t)(oi + 64) * D;

    for (int kk = 0; kk < D; kk += 8) {
        float4 w00 = *(const float4*)(w0p + kk);
        float4 w01 = *(const float4*)(w0p + kk + 4);
        float4 w10 = *(const float4*)(w1p + kk);
        float4 w11 = *(const float4*)(w1p + kk + 4);
        #pragma unroll
        for (int n = 0; n < 16; ++n) {
            const float* hp = &tile[(q * 16 + n) * D + kk];
            float4 a = *(const float4*)hp;
            float4 b = *(const float4*)(hp + 4);
            acc0[n] += a.x * w00.x + a.y * w00.y + a.z * w00.z + a.w * w00.w
                     + b.x * w01.x + b.y * w01.y + b.z * w01.z + b.w * w01.w;
            acc1[n] += a.x * w10.x + a.y * w10.y + a.z * w10.z + a.w * w10.w
                     + b.x * w11.x + b.y * w11.y + b.z * w11.z + b.w * w11.w;
        }
    }

    #pragma unroll
    for (int n = 0; n < 16; ++n) {
        int node = q * 16 + n;
        if (node < nvalid) {
            size_t base = (size_t)(n0 + node) * D;
            out[base + oi]      = acc0[n];
            out[base + oi + 64] = acc1[n];
        }
    }
}

// ---------------------------------------------------------------------------
// K2: per-node attention scores s_src = z . wa[:D], s_dst = z . wa[D:2D]
// ---------------------------------------------------------------------------
__global__ __launch_bounds__(256) void node_scores(
    const float* __restrict__ z, const float* __restrict__ wa,
    float* __restrict__ s_src, float* __restrict__ s_dst, int N)
{
    const int lane = threadIdx.x & 63;
    const int n = blockIdx.x * 4 + (threadIdx.x >> 6);
    if (n >= N) return;
    float2 zv = *(const float2*)(z + (size_t)n * D + 2 * lane);
    float a = zv.x * wa[2 * lane]     + zv.y * wa[2 * lane + 1];
    float b = zv.x * wa[D + 2 * lane] + zv.y * wa[D + 2 * lane + 1];
    #pragma unroll
    for (int off = 32; off > 0; off >>= 1) {
        a += __shfl_xor(a, off, 64);
        b += __shfl_xor(b, off, 64);
    }
    if (lane == 0) { s_src[n] = a; s_dst[n] = b; }
}

// ---------------------------------------------------------------------------
// K3a: histogram of dst -> deg[N]  (thread-per-edge, TLP hides atomic latency)
// ---------------------------------------------------------------------------
__global__ __launch_bounds__(256) void hist_kernel(
    const int* __restrict__ dst, int* __restrict__ deg, int E)
{
    int e = blockIdx.x * blockDim.x + threadIdx.x;
    if (e < E) atomicAdd(deg + dst[e], 1);
}

// ---------------------------------------------------------------------------
// K3b/c/d: 3-phase exclusive scan of deg -> off, cursor (NB <= 256 blocks)
// ---------------------------------------------------------------------------
__global__ __launch_bounds__(256) void scan_block_sums(
    const int* __restrict__ deg, int* __restrict__ bsum, int N)
{
    __shared__ int s[256];
    int i = blockIdx.x * 256 + threadIdx.x;
    s[threadIdx.x] = (i < N) ? deg[i] : 0;
    for (int o = 128; o > 0; o >>= 1) {
        __syncthreads();
        if (threadIdx.x < o) s[threadIdx.x] += s[threadIdx.x + o];
    }
    if (threadIdx.x == 0) bsum[blockIdx.x] = s[0];
}

__global__ __launch_bounds__(256) void scan_bsum(
    const int* __restrict__ bsum, int* __restrict__ boff, int NB)
{
    __shared__ int s[256];
    int t = threadIdx.x;
    int v = (t < NB) ? bsum[t] : 0;
    s[t] = v;
    for (int o = 1; o < 256; o <<= 1) {
        __syncthreads();
        int x = (t >= o) ? s[t - o] : 0;
        __syncthreads();
        s[t] += x;
    }
    __syncthreads();
    if (t < NB) boff[t] = s[t] - v;   // exclusive
}

__global__ __launch_bounds__(256) void scan_final(
    const int* __restrict__ deg, const int* __restrict__ boff,
    int* __restrict__ off, int* __restrict__ cursor, int N)
{
    __shared__ int s[256];
    int t = threadIdx.x;
    int i = blockIdx.x * 256 + t;
    int v = (i < N) ? deg[i] : 0;
    s[t] = v;
    for (int o = 1; o < 256; o <<= 1) {
        __syncthreads();
        int x = (t >= o) ? s[t - o] : 0;
        __syncthreads();
        s[t] += x;
    }
    __syncthreads();
    if (i < N) {
        int ex = boff[blockIdx.x] + s[t] - v;
        off[i] = ex;
        cursor[i] = ex;
    }
}

// ---------------------------------------------------------------------------
// K_matvec: s_e[e] = edge_w[e] . wa_e   — pure streaming GEMV, no gathers.
// 16 lanes per edge; 4 edges per wave (consecutive) -> wave reads 2 KB
// contiguous per iteration via dwordx4. 4-step shuffle reduce within 16.
// ---------------------------------------------------------------------------
__global__ __launch_bounds__(256) void edge_matvec(
    const float* __restrict__ edge_w, const float* __restrict__ wa,
    float* __restrict__ s_e, int E)
{
    const int lg = threadIdx.x & 15;                        // lane in 16-group
    const int g0 = (blockIdx.x * blockDim.x + threadIdx.x) >> 4;
    const int ng = (gridDim.x * blockDim.x) >> 4;
    // per-lane slice of wa_e: elements [lg*8, lg*8+8)
    const float4* wa4 = (const float4*)(wa + 2 * D);
    const float4 w0 = wa4[2 * lg];
    const float4 w1 = wa4[2 * lg + 1];
    for (int e = g0; e < E; e += ng) {
        const float4* ewp = (const float4*)(edge_w + (size_t)e * D);
        float4 a = ewp[2 * lg];
        float4 b = ewp[2 * lg + 1];
        float p = a.x * w0.x + a.y * w0.y + a.z * w0.z + a.w * w0.w
                + b.x * w1.x + b.y * w1.y + b.z * w1.z + b.w * w1.w;
        p += __shfl_xor(p, 1, 16);
        p += __shfl_xor(p, 2, 16);
        p += __shfl_xor(p, 4, 16);
        p += __shfl_xor(p, 8, 16);
        if (lg == 0) s_e[e] = p;
    }
}

// ---------------------------------------------------------------------------
// K_scatter: thread-per-edge. ex = exp(leaky_relu(s_src[s]+s_dst[d]+s_e[e]));
// one atomic bump of cursor[d]; write {src,ex} into the dst bucket.
// (logits are O(15): exp never overflows fp32 -> max-subtraction skipped;
//  normalization deferred to agg_finalize)
// ---------------------------------------------------------------------------
__global__ __launch_bounds__(256) void edge_scatter(
    const int* __restrict__ src, const int* __restrict__ dst,
    const float* __restrict__ s_src, const float* __restrict__ s_dst,
    const float* __restrict__ s_e, int* __restrict__ cursor,
    int* __restrict__ src_s, float* __restrict__ ex_s, int E)
{
    int e = blockIdx.x * blockDim.x + threadIdx.x;
    if (e >= E) return;
    int s = src[e];
    int d = dst[e];
    float logit = s_src[s] + s_dst[d] + s_e[e];
    logit = (logit > 0.f) ? logit : 0.01f * logit;
    float ex = __expf(logit);
    int pos = atomicAdd(cursor + d, 1);
    src_s[pos] = s;
    ex_s[pos]  = ex;
}

// ---------------------------------------------------------------------------
// K4: aggregation + epilogue, no atomics. One wave per dst node.
// Cooperative bucket load: 64 (src,ex) pairs vector-loaded once, then
// broadcast via shfl -> z-gathers are independent and pipeline.
//  out = h + relu(deg>0 ? h_s + agg/denom : h)   (h_s lives in d_out)
// ---------------------------------------------------------------------------
__global__ __launch_bounds__(256) void agg_finalize(
    const int* __restrict__ off, const int* __restrict__ deg,
    const int* __restrict__ src_s, const float* __restrict__ ex_s,
    const float* __restrict__ z, const float* __restrict__ h,
    const float* __restrict__ h_s, float* __restrict__ out, int N)
{
    const int lane = threadIdx.x & 63;
    const int n = blockIdx.x * 4 + (threadIdx.x >> 6);
    if (n >= N) return;
    const int b  = off[n];
    const int dg = deg[n];
    float ax = 0.f, ay = 0.f, dsum = 0.f;
    for (int base = 0; base < dg; base += 64) {
        const int cnt = min(64, dg - base);
        const int idx = b + base + ((lane < cnt) ? lane : 0);
        int   sv = src_s[idx];
        float ev = ex_s[idx];
        for (int j = 0; j < cnt; ++j) {
            int   s  = __shfl(sv, j, 64);
            float ex = __shfl(ev, j, 64);
            dsum += ex;
            float2 zv = *(const float2*)(z + (size_t)s * D + 2 * lane);
            ax += ex * zv.x;
            ay += ex * zv.y;
        }
    }
    float2 hv = *(const float2*)(h + (size_t)n * D + 2 * lane);
    float rx, ry;
    if (dg > 0) {
        float inv = 1.f / fmaxf(dsum, 1e-9f);
        float2 hs = *(const float2*)(h_s + (size_t)n * D + 2 * lane);
        rx = hs.x + ax * inv;
        ry = hs.y + ay * inv;
    } else {
        rx = hv.x; ry = hv.y;
    }
    rx = fmaxf(rx, 0.f); ry = fmaxf(ry, 0.f);
    float2 o = make_float2(hv.x + rx, hv.y + ry);
    *(float2*)(out + (size_t)n * D + 2 * lane) = o;
}

// ---------------------------------------------------------------------------
extern "C" void kernel_launch(void* const* d_in, const int* in_sizes, int n_in,
                              void* d_out, int out_size, void* d_ws, size_t ws_size,
                              hipStream_t stream)
{
    const float* h      = (const float*)d_in[0];
    const float* edge_w = (const float*)d_in[1];
    const float* W_self = (const float*)d_in[2];
    const float* W_func = (const float*)d_in[3];
    const float* W_att  = (const float*)d_in[4];
    const int*   src    = (const int*)d_in[5];
    const int*   dst    = (const int*)d_in[6];
    float* out = (float*)d_out;

    const int N = in_sizes[0] / D;   // 50000
    const int E = in_sizes[1] / D;   // 800000
    const int NB = (N + 255) / 256;  // 196 scan blocks (<= 256 required)

    // workspace layout (floats/ints)
    float* z     = (float*)d_ws;           // N*D
    float* ex_s  = z + (size_t)N * D;      // E
    float* s_e   = ex_s + E;               // E
    float* s_src = s_e + E;                // N
    float* s_dst = s_src + N;              // N
    int*   src_s = (int*)(s_dst + N);      // E
    int*   deg   = src_s + E;              // N
    int*   off   = deg + N;                // N
    int*   cursor= off + N;                // N
    int*   bsum  = cursor + N;             // 256
    int*   boff  = bsum + 256;             // 256

    // zero deg (memset is graph-capture safe)
    hipMemsetAsync(deg, 0, (size_t)N * sizeof(int), stream);

    // K1: node transforms (y=0 -> z, y=1 -> h_s staged in d_out)
    {
        dim3 grid((N + NT - 1) / NT, 2);
        node_transform<<<grid, 256, 0, stream>>>(h, W_func, W_self, z, out, N);
    }
    // K2: per-node attention scores
    node_scores<<<(N + 3) / 4, 256, 0, stream>>>(z, W_att, s_src, s_dst, N);

    // edge scalar scores (pure streaming)
    edge_matvec<<<2048, 256, 0, stream>>>(edge_w, W_att, s_e, E);

    // CSR build
    hist_kernel<<<(E + 255) / 256, 256, 0, stream>>>(dst, deg, E);
    scan_block_sums<<<NB, 256, 0, stream>>>(deg, bsum, N);
    scan_bsum<<<1, 256, 0, stream>>>(bsum, boff, NB);
    scan_final<<<NB, 256, 0, stream>>>(deg, boff, off, cursor, N);

    // bucket scatter (thread-per-edge; atomic hidden by TLP)
    edge_scatter<<<(E + 255) / 256, 256, 0, stream>>>(src, dst, s_src, s_dst,
                                                      s_e, cursor, src_s, ex_s, E);

    // K4: bucketed aggregation + epilogue (no atomics)
    agg_finalize<<<(N + 3) / 4, 256, 0, stream>>>(off, deg, src_s, ex_s,
                                                  z, h, out, out, N);
}

// Round 4
// 794.133 us; speedup vs baseline: 1.5636x; 1.0248x over previous
//
#include <hip/hip_runtime.h>
#include <hip/hip_bf16.h>
#include <math.h>

#define D 128
constexpr int NT = 64;  // nodes per block in node_transform

// ---------------------------------------------------------------------------
// K1: z = h @ W_func^T (blockIdx.y==0)   h_s = h @ W_self^T (blockIdx.y==1)
// 64-node tile in LDS. Thread t: oi = t&31 -> 4 outputs {oi,oi+32,oi+64,oi+96},
// q = t>>5 -> 8 nodes [q*8, q*8+8). 1 FMA per LDS byte (2x better than the
// 2-output variant): tile element read by 32 threads instead of 64.
// ---------------------------------------------------------------------------
__global__ __launch_bounds__(256) void node_transform(
    const float* __restrict__ h, const float* __restrict__ Wf,
    const float* __restrict__ Ws, float* __restrict__ z,
    float* __restrict__ hs_out, int N)
{
    __shared__ float tile[NT * D];  // 32 KB
    const int t = threadIdx.x;
    const int n0 = blockIdx.x * NT;
    const float* __restrict__ W = (blockIdx.y == 0) ? Wf : Ws;
    float* __restrict__ out = (blockIdx.y == 0) ? z : hs_out;
    const int nvalid = min(NT, N - n0);

    {   // stage h tile: 2048 float4, coalesced
        const float4* __restrict__ src4 = (const float4*)(h + (size_t)n0 * D);
        float4* dst4 = (float4*)tile;
        #pragma unroll
        for (int i = 0; i < 8; ++i) {
            int idx = t + i * 256;               // float4 index; node = idx>>5
            float4 v = make_float4(0.f, 0.f, 0.f, 0.f);
            if ((idx >> 5) < nvalid) v = src4[idx];
            dst4[idx] = v;
        }
    }
    __syncthreads();

    const int oi = t & 31;
    const int q  = t >> 5;
    float acc[8][4];
    #pragma unroll
    for (int n = 0; n < 8; ++n)
        #pragma unroll
        for (int m = 0; m < 4; ++m) acc[n][m] = 0.f;

    for (int kk = 0; kk < D; kk += 8) {
        float4 w[4][2];
        #pragma unroll
        for (int m = 0; m < 4; ++m) {
            const float* wr = W + (size_t)(oi + 32 * m) * D + kk;
            w[m][0] = *(const float4*)wr;
            w[m][1] = *(const float4*)(wr + 4);
        }
        #pragma unroll
        for (int n = 0; n < 8; ++n) {
            const float* hp = &tile[(q * 8 + n) * D + kk];
            float4 a = *(const float4*)hp;
            float4 b = *(const float4*)(hp + 4);
            #pragma unroll
            for (int m = 0; m < 4; ++m) {
                acc[n][m] += a.x * w[m][0].x + a.y * w[m][0].y
                           + a.z * w[m][0].z + a.w * w[m][0].w
                           + b.x * w[m][1].x + b.y * w[m][1].y
                           + b.z * w[m][1].z + b.w * w[m][1].w;
            }
        }
    }

    #pragma unroll
    for (int n = 0; n < 8; ++n) {
        int node = q * 8 + n;
        if (node < nvalid) {
            float* op = out + (size_t)(n0 + node) * D + oi;
            #pragma unroll
            for (int m = 0; m < 4; ++m) op[32 * m] = acc[n][m];
        }
    }
}

// ---------------------------------------------------------------------------
// K2: per-node attention scores s_src = z . wa[:D], s_dst = z . wa[D:2D]
// ---------------------------------------------------------------------------
__global__ __launch_bounds__(256) void node_scores(
    const float* __restrict__ z, const float* __restrict__ wa,
    float* __restrict__ s_src, float* __restrict__ s_dst, int N)
{
    const int lane = threadIdx.x & 63;
    const int n = blockIdx.x * 4 + (threadIdx.x >> 6);
    if (n >= N) return;
    float2 zv = *(const float2*)(z + (size_t)n * D + 2 * lane);
    float a = zv.x * wa[2 * lane]     + zv.y * wa[2 * lane + 1];
    float b = zv.x * wa[D + 2 * lane] + zv.y * wa[D + 2 * lane + 1];
    #pragma unroll
    for (int off = 32; off > 0; off >>= 1) {
        a += __shfl_xor(a, off, 64);
        b += __shfl_xor(b, off, 64);
    }
    if (lane == 0) { s_src[n] = a; s_dst[n] = b; }
}

// ---------------------------------------------------------------------------
// K3: s_e[e] = edge_w[e] . wa_e  (pure streaming GEMV) + fused dst histogram.
// 16 lanes per edge; 4 consecutive edges per wave -> 2 KB contiguous reads.
// Histogram atomic is non-returning -> fire-and-forget, hidden under the
// BW-bound stream.
// ---------------------------------------------------------------------------
__global__ __launch_bounds__(256) void edge_matvec_hist(
    const float* __restrict__ edge_w, const float* __restrict__ wa,
    const int* __restrict__ dst, float* __restrict__ s_e,
    int* __restrict__ deg, int E)
{
    const int lg = threadIdx.x & 15;                        // lane in 16-group
    const int g0 = (blockIdx.x * blockDim.x + threadIdx.x) >> 4;
    const int ng = (gridDim.x * blockDim.x) >> 4;
    const float4* wa4 = (const float4*)(wa + 2 * D);
    const float4 w0 = wa4[2 * lg];
    const float4 w1 = wa4[2 * lg + 1];
    for (int e = g0; e < E; e += ng) {
        const float4* ewp = (const float4*)(edge_w + (size_t)e * D);
        float4 a = ewp[2 * lg];
        float4 b = ewp[2 * lg + 1];
        float p = a.x * w0.x + a.y * w0.y + a.z * w0.z + a.w * w0.w
                + b.x * w1.x + b.y * w1.y + b.z * w1.z + b.w * w1.w;
        p += __shfl_xor(p, 1, 16);
        p += __shfl_xor(p, 2, 16);
        p += __shfl_xor(p, 4, 16);
        p += __shfl_xor(p, 8, 16);
        if (lg == 0) {
            s_e[e] = p;
            atomicAdd(deg + dst[e], 1);   // non-returning: no stall
        }
    }
}

// ---------------------------------------------------------------------------
// Scan: 3-phase exclusive scan of deg -> off, cursor (NB <= 256 blocks)
// ---------------------------------------------------------------------------
__global__ __launch_bounds__(256) void scan_block_sums(
    const int* __restrict__ deg, int* __restrict__ bsum, int N)
{
    __shared__ int s[256];
    int i = blockIdx.x * 256 + threadIdx.x;
    s[threadIdx.x] = (i < N) ? deg[i] : 0;
    for (int o = 128; o > 0; o >>= 1) {
        __syncthreads();
        if (threadIdx.x < o) s[threadIdx.x] += s[threadIdx.x + o];
    }
    if (threadIdx.x == 0) bsum[blockIdx.x] = s[0];
}

__global__ __launch_bounds__(256) void scan_bsum(
    const int* __restrict__ bsum, int* __restrict__ boff, int NB)
{
    __shared__ int s[256];
    int t = threadIdx.x;
    int v = (t < NB) ? bsum[t] : 0;
    s[t] = v;
    for (int o = 1; o < 256; o <<= 1) {
        __syncthreads();
        int x = (t >= o) ? s[t - o] : 0;
        __syncthreads();
        s[t] += x;
    }
    __syncthreads();
    if (t < NB) boff[t] = s[t] - v;   // exclusive
}

__global__ __launch_bounds__(256) void scan_final(
    const int* __restrict__ deg, const int* __restrict__ boff,
    int* __restrict__ off, int* __restrict__ cursor, int N)
{
    __shared__ int s[256];
    int t = threadIdx.x;
    int i = blockIdx.x * 256 + t;
    int v = (i < N) ? deg[i] : 0;
    s[t] = v;
    for (int o = 1; o < 256; o <<= 1) {
        __syncthreads();
        int x = (t >= o) ? s[t - o] : 0;
        __syncthreads();
        s[t] += x;
    }
    __syncthreads();
    if (i < N) {
        int ex = boff[blockIdx.x] + s[t] - v;
        off[i] = ex;
        cursor[i] = ex;
    }
}

// ---------------------------------------------------------------------------
// K_scatter: thread-per-edge. ex = exp(leaky_relu(s_src[s]+s_dst[d]+s_e[e]));
// one cursor atomic; ONE packed 8B store {src, ex} into the dst bucket.
// (logits are O(15): fp32 exp can't overflow -> max-subtraction skipped;
//  normalization deferred to agg_finalize)
// ---------------------------------------------------------------------------
__global__ __launch_bounds__(256) void edge_scatter(
    const int* __restrict__ src, const int* __restrict__ dst,
    const float* __restrict__ s_src, const float* __restrict__ s_dst,
    const float* __restrict__ s_e, int* __restrict__ cursor,
    int2* __restrict__ bkt, int E)
{
    int e = blockIdx.x * blockDim.x + threadIdx.x;
    if (e >= E) return;
    int s = src[e];
    int d = dst[e];
    float logit = s_src[s] + s_dst[d] + s_e[e];
    logit = (logit > 0.f) ? logit : 0.01f * logit;
    float ex = __expf(logit);
    int pos = atomicAdd(cursor + d, 1);
    bkt[pos] = make_int2(s, __float_as_int(ex));
}

// ---------------------------------------------------------------------------
// K4: aggregation + epilogue, no atomics. One wave per dst node.
// Unroll-by-8 chunks: 8 wave-uniform bucket loads (L1 broadcast) then 8
// INDEPENDENT z-gathers in flight -> latency hidden (the round-3 version had
// a serial shfl->gather chain, ~1 gather in flight).
//  out = h + relu(deg>0 ? h_s + agg/denom : h)   (h_s lives in d_out)
// ---------------------------------------------------------------------------
__global__ __launch_bounds__(256) void agg_finalize(
    const int* __restrict__ off, const int* __restrict__ deg,
    const int2* __restrict__ bkt, const float* __restrict__ z,
    const float* __restrict__ h, const float* __restrict__ h_s,
    float* __restrict__ out, int N)
{
    const int lane = threadIdx.x & 63;
    const int n = blockIdx.x * 4 + (threadIdx.x >> 6);
    if (n >= N) return;
    const int b  = off[n];
    const int dg = deg[n];
    float ax = 0.f, ay = 0.f, dsum = 0.f;
    int e = 0;
    for (; e + 8 <= dg; e += 8) {
        int2 p[8];
        #pragma unroll
        for (int j = 0; j < 8; ++j) p[j] = bkt[b + e + j];
        float2 zv[8];
        #pragma unroll
        for (int j = 0; j < 8; ++j)
            zv[j] = *(const float2*)(z + (size_t)p[j].x * D + 2 * lane);
        #pragma unroll
        for (int j = 0; j < 8; ++j) {
            float ex = __int_as_float(p[j].y);
            dsum += ex;
            ax += ex * zv[j].x;
            ay += ex * zv[j].y;
        }
    }
    for (; e < dg; ++e) {
        int2 p = bkt[b + e];
        float ex = __int_as_float(p.y);
        float2 zv = *(const float2*)(z + (size_t)p.x * D + 2 * lane);
        dsum += ex;
        ax += ex * zv.x;
        ay += ex * zv.y;
    }
    float2 hv = *(const float2*)(h + (size_t)n * D + 2 * lane);
    float rx, ry;
    if (dg > 0) {
        float inv = 1.f / fmaxf(dsum, 1e-9f);
        float2 hs = *(const float2*)(h_s + (size_t)n * D + 2 * lane);
        rx = hs.x + ax * inv;
        ry = hs.y + ay * inv;
    } else {
        rx = hv.x; ry = hv.y;
    }
    rx = fmaxf(rx, 0.f); ry = fmaxf(ry, 0.f);
    float2 o = make_float2(hv.x + rx, hv.y + ry);
    *(float2*)(out + (size_t)n * D + 2 * lane) = o;
}

// ---------------------------------------------------------------------------
extern "C" void kernel_launch(void* const* d_in, const int* in_sizes, int n_in,
                              void* d_out, int out_size, void* d_ws, size_t ws_size,
                              hipStream_t stream)
{
    const float* h      = (const float*)d_in[0];
    const float* edge_w = (const float*)d_in[1];
    const float* W_self = (const float*)d_in[2];
    const float* W_func = (const float*)d_in[3];
    const float* W_att  = (const float*)d_in[4];
    const int*   src    = (const int*)d_in[5];
    const int*   dst    = (const int*)d_in[6];
    float* out = (float*)d_out;

    const int N = in_sizes[0] / D;   // 50000
    const int E = in_sizes[1] / D;   // 800000
    const int NB = (N + 255) / 256;  // 196 scan blocks (<= 256 required)

    // workspace layout
    float* z     = (float*)d_ws;           // N*D
    float* s_e   = z + (size_t)N * D;      // E
    float* s_src = s_e + E;                // N
    float* s_dst = s_src + N;              // N
    int2*  bkt   = (int2*)(s_dst + N);     // E int2 (8B-aligned: offset even)
    int*   deg   = (int*)(bkt + E);        // N
    int*   off   = deg + N;                // N
    int*   cursor= off + N;                // N
    int*   bsum  = cursor + N;             // 256
    int*   boff  = bsum + 256;             // 256

    // zero deg (memset is graph-capture safe)
    hipMemsetAsync(deg, 0, (size_t)N * sizeof(int), stream);

    // K1: node transforms (y=0 -> z, y=1 -> h_s staged in d_out)
    {
        dim3 grid((N + NT - 1) / NT, 2);
        node_transform<<<grid, 256, 0, stream>>>(h, W_func, W_self, z, out, N);
    }
    // K2: per-node attention scores
    node_scores<<<(N + 3) / 4, 256, 0, stream>>>(z, W_att, s_src, s_dst, N);

    // K3: edge scalar scores + dst histogram (fused, BW-bound)
    edge_matvec_hist<<<2048, 256, 0, stream>>>(edge_w, W_att, dst, s_e, deg, E);

    // scan deg -> off/cursor
    scan_block_sums<<<NB, 256, 0, stream>>>(deg, bsum, N);
    scan_bsum<<<1, 256, 0, stream>>>(bsum, boff, NB);
    scan_final<<<NB, 256, 0, stream>>>(deg, boff, off, cursor, N);

    // bucket scatter (thread-per-edge; atomic hidden by TLP; packed 8B store)
    edge_scatter<<<(E + 255) / 256, 256, 0, stream>>>(src, dst, s_src, s_dst,
                                                      s_e, cursor, bkt, E);

    // K4: bucketed aggregation + epilogue (no atomics, pipelined gathers)
    agg_finalize<<<(N + 3) / 4, 256, 0, stream>>>(off, deg, bkt, z, h, out, out, N);
}